// Round 6
// baseline (236.979 us; speedup 1.0000x reference)
//
#include <hip/hip_runtime.h>
#include <stdint.h>
#include <math.h>

#define SLEN 2048
#define EPT 16               // elements per lane: half a row per wave
#define NTHREADS 256         // 4 waves = 2 pairs; each pair = 2 waves = 1 row
#define CPW 4                // chunks (of 256 el) per wave; row = 8 chunks
#define DSEQ 4               // sequential rows per pair (software pipeline depth)
#define TOKENS_PER_OUT 8388608   // 1024*4*2048

// ---------- Threefry-2x32, 20 rounds, matches jax._src.prng ----------
__host__ __device__ __forceinline__ void tf2x32(uint32_t k0, uint32_t k1,
                                                uint32_t x0, uint32_t x1,
                                                uint32_t &o0, uint32_t &o1) {
  uint32_t ks2 = 0x1BD11BDAu ^ k0 ^ k1;
  x0 += k0; x1 += k1;
#define TFR(r) { x0 += x1; x1 = (x1 << (r)) | (x1 >> (32 - (r))); x1 ^= x0; }
  TFR(13) TFR(15) TFR(26) TFR(6)
  x0 += k1;  x1 += ks2 + 1u;
  TFR(17) TFR(29) TFR(16) TFR(24)
  x0 += ks2; x1 += k0 + 2u;
  TFR(13) TFR(15) TFR(26) TFR(6)
  x0 += k0;  x1 += k1 + 3u;
  TFR(17) TFR(29) TFR(16) TFR(24)
  x0 += k1;  x1 += ks2 + 4u;
  TFR(13) TFR(15) TFR(26) TFR(6)
  x0 += ks2; x1 += k0 + 5u;
#undef TFR
  o0 = x0; o1 = x1;
}

// 4 independent threefry streams; sched_barrier after each round keeps the
// 4-wide interleave intact through the machine scheduler.
__device__ __forceinline__ void tf4_bits(uint32_t k0, uint32_t k1,
                                         uint32_t cbase, uint32_t bits[4]) {
  const uint32_t ks2 = 0x1BD11BDAu ^ k0 ^ k1;
  uint32_t x0[4], x1[4];
#pragma unroll
  for (int i = 0; i < 4; ++i) { x0[i] = k0; x1[i] = (cbase + (uint32_t)i) + k1; }
#define TFR4(r)                                                         \
  _Pragma("unroll")                                                     \
  for (int i = 0; i < 4; ++i) {                                         \
    x0[i] += x1[i];                                                     \
    x1[i] = (x1[i] << (r)) | (x1[i] >> (32 - (r)));                     \
    x1[i] ^= x0[i];                                                     \
  }                                                                     \
  __builtin_amdgcn_sched_barrier(0);
#define INJ4(a, b)                                                      \
  _Pragma("unroll")                                                     \
  for (int i = 0; i < 4; ++i) { x0[i] += (a); x1[i] += (b); }
  TFR4(13) TFR4(15) TFR4(26) TFR4(6)
  INJ4(k1, ks2 + 1u)
  TFR4(17) TFR4(29) TFR4(16) TFR4(24)
  INJ4(ks2, k0 + 2u)
  TFR4(13) TFR4(15) TFR4(26) TFR4(6)
  INJ4(k0, k1 + 3u)
  TFR4(17) TFR4(29) TFR4(16) TFR4(24)
  INJ4(k1, ks2 + 4u)
  TFR4(13) TFR4(15) TFR4(26) TFR4(6)
  INJ4(ks2, k0 + 5u)
#undef TFR4
#undef INJ4
#pragma unroll
  for (int i = 0; i < 4; ++i) bits[i] = x0[i] ^ x1[i];
}

__device__ __forceinline__ float u01_from_bits(uint32_t bits) {
  return __uint_as_float((bits >> 9) | 0x3F800000u) - 1.0f;
}

#define SBAR() __builtin_amdgcn_sched_barrier(0)

// 8 correctly-rounded-quality f32 logs (positive normal f32 inputs), staged
// 8-wide with hard sched barriers so dependent f64 ops sit ~8 instrs apart.
// Bit-identical to the verified scalar math:
//   x = 2^e * m, m in [sqrt2/2, sqrt2), r = (m-1)*rcp(m+1) w/ 1 Newton,
//   log = e*ln2 + 2r*(1 + t/3 + .. + t^6/13).
__device__ __forceinline__ void log8_cr(const float x[8], float out[8]) {
#pragma clang fp contract(off)
  double m[8]; int e[8];
#pragma unroll
  for (int i = 0; i < 8; ++i) {
    uint32_t xb   = __float_as_uint(x[i]);
    uint32_t mant = xb & 0x7FFFFFu;
    int      ee   = (int)(xb >> 23) - 127;
    bool     big  = mant > 0x3504F3u;          // m > sqrt(2)
    e[i] = ee + (big ? 1 : 0);
    uint32_t hi = (big ? 0x3FE00000u : 0x3FF00000u) | (mant >> 3);
    uint32_t lo = mant << 29;
    m[i] = __longlong_as_double(((long long)hi << 32) | (long long)lo);
  }
  SBAR();
  double mp1[8];
#pragma unroll
  for (int i = 0; i < 8; ++i) mp1[i] = m[i] + 1.0;
  SBAR();
  double y[8];
#pragma unroll
  for (int i = 0; i < 8; ++i) y[i] = __builtin_amdgcn_rcp(mp1[i]);
  SBAR();
#pragma unroll
  for (int i = 0; i < 8; ++i) y[i] = fma(fma(-mp1[i], y[i], 1.0), y[i], y[i]);
  SBAR();
  double r[8];
#pragma unroll
  for (int i = 0; i < 8; ++i) r[i] = (m[i] - 1.0) * y[i];
  SBAR();
  double t[8];
#pragma unroll
  for (int i = 0; i < 8; ++i) t[i] = r[i] * r[i];
  SBAR();
  double p[8];
#pragma unroll
  for (int i = 0; i < 8; ++i) p[i] = fma(0.07692307692307693, t[i], 0.09090909090909091);
  SBAR();
#pragma unroll
  for (int i = 0; i < 8; ++i) p[i] = fma(p[i], t[i], 0.1111111111111111);
  SBAR();
#pragma unroll
  for (int i = 0; i < 8; ++i) p[i] = fma(p[i], t[i], 0.14285714285714285);
  SBAR();
#pragma unroll
  for (int i = 0; i < 8; ++i) p[i] = fma(p[i], t[i], 0.2);
  SBAR();
#pragma unroll
  for (int i = 0; i < 8; ++i) p[i] = fma(p[i], t[i], 0.3333333333333333);
  SBAR();
#pragma unroll
  for (int i = 0; i < 8; ++i) p[i] = fma(p[i], t[i], 1.0);
  SBAR();
#pragma unroll
  for (int i = 0; i < 8; ++i) r[i] = r[i] + r[i];       // 2r (exact)
  SBAR();
#pragma unroll
  for (int i = 0; i < 8; ++i) p[i] = r[i] * p[i];       // 2r*q
  SBAR();
#pragma unroll
  for (int i = 0; i < 8; ++i)
    out[i] = (float)fma((double)e[i], 0.6931471805599453, p[i]);
}

// scalar CR log (erfinv path only; same math, unstaged)
__device__ __forceinline__ float log_cr(float x) {
#pragma clang fp contract(off)
  uint32_t xb   = __float_as_uint(x);
  uint32_t mant = xb & 0x7FFFFFu;
  int      e    = (int)(xb >> 23) - 127;
  bool     big  = mant > 0x3504F3u;
  e += big ? 1 : 0;
  uint32_t hi = (big ? 0x3FE00000u : 0x3FF00000u) | (mant >> 3);
  double m = __longlong_as_double(((long long)hi << 32) | (long long)(mant << 29));
  double mp1 = m + 1.0;
  double y = __builtin_amdgcn_rcp(mp1);
  y = fma(fma(-mp1, y, 1.0), y, y);
  double r = (m - 1.0) * y;
  double t = r * r;
  double p = fma(0.07692307692307693, t, 0.09090909090909091);
  p = fma(p, t, 0.1111111111111111);
  p = fma(p, t, 0.14285714285714285);
  p = fma(p, t, 0.2);
  p = fma(p, t, 0.3333333333333333);
  p = fma(p, t, 1.0);
  return (float)fma((double)e, 0.6931471805599453, (r + r) * p);
}

// XLA ErfInv f32 expander (Giles poly), log1p per ElementalIrEmitter::EmitLog1p
__device__ float erfinv_xla(float x) {
#pragma clang fp contract(off)
  float x2  = x * x;
  float nx2 = -x2;
  float l1p;
  if (fabsf(nx2) < 1e-4f) {
    l1p = (-0.5f * nx2 + 1.0f) * nx2;
  } else {
    l1p = log_cr(1.0f + nx2);
  }
  float w = -l1p;
  float p;
  if (w < 5.0f) {
    float ww = w - 2.5f;
    p = 2.81022636e-08f;
    p = p * ww + 3.43273939e-07f;
    p = p * ww + -3.5233877e-06f;
    p = p * ww + -4.39150654e-06f;
    p = p * ww + 0.00021858087f;
    p = p * ww + -0.00125372503f;
    p = p * ww + -0.00417768164f;
    p = p * ww + 0.246640727f;
    p = p * ww + 1.50140941f;
  } else {
    float ww = sqrtf(w) - 3.0f;
    p = -0.000200214257f;
    p = p * ww + 0.000100950558f;
    p = p * ww + 0.00134934322f;
    p = p * ww + -0.00367342844f;
    p = p * ww + 0.00573950773f;
    p = p * ww + -0.0076224613f;
    p = p * ww + 0.00943887047f;
    p = p * ww + 1.00167406f;
    p = p * ww + 2.83297682f;
  }
  return p * x;
}

// R6: deep software pipeline, loads a FULL ROW ahead. Serial-phase model from
// R0-R5 invariants: per wave [load -> 12k-cy compute -> DS select -> store]
// phases never overlap chip-wide (homogeneous co-launched waves), so memory
// time ADDS to the 41us VALU floor. Fix: each 2-wave pair runs DSEQ=4 rows;
// next row's attn+w+ids (12KB/wave) are issued at the TOP of each row, first
// used one full compute phase later -> HBM services them under the f64
// pipeline. Stores are fire-and-forget (vmcnt is FIFO; loads issue before
// stores each row, so waiting on loads never drains stores). 256-thr blocks
// hold 2 independent pairs; radix-select runs a UNIFORM 4 passes (done-flag
// skips work, not barriers) so barriers are safe across pairs. Rolled row
// loop (I$) + named C/N regs with explicit copies (no dynamic indexing).
__global__ __launch_bounds__(NTHREADS, 2)
void gumbel_topk_mask(const float* __restrict__ wfull,   // (B,C,2S) f32
                      const int*   __restrict__ attn,    // (B,C,S) i32
                      const int*   __restrict__ ids,     // (B,C,S) i32
                      int* __restrict__ out,             // 3x(B,C,S) i32 concat
                      uint32_t kg0, uint32_t kg1, uint32_t kn0, uint32_t kn1) {
#pragma clang fp contract(off)
  const int t    = threadIdx.x;
  const int lane = t & 63;
  const int wid  = t >> 6;            // 0..3
  const int pid  = wid >> 1;          // pair id: 0 or 1
  const int wl   = wid & 1;           // half-row within pair

  __shared__ __align__(16) uint32_t hist[2][2][256];   // [pair][pingpong][bins]
  __shared__ uint32_t wsum[2][2];
  __shared__ uint32_t wtot[2][2];

  const int row0 = (blockIdx.x * 2 + pid) * DSEQ;

  // ---- prologue: row0 inputs ----
  int4 attnC[CPW]; float4 wC[CPW]; int4 idsC[CPW];
  {
    const size_t rb = (size_t)row0 * SLEN;
    const int4*   av4 = (const int4*)(attn + rb);
    const float4* wv4 = (const float4*)(wfull + 2 * rb);
    const int4*   iv4 = (const int4*)(ids + rb);
#pragma unroll
    for (int j = 0; j < CPW; ++j) {
      attnC[j] = av4[64 * (CPW * wl + j) + lane];
      wC[j]    = wv4[64 * (CPW * wl + j) + lane];
      idsC[j]  = iv4[64 * (CPW * wl + j) + lane];
    }
  }

  for (int rr = 0; rr < DSEQ; ++rr) {
    const int row = row0 + rr;
    const size_t rbase = (size_t)row * SLEN;

    // ---- issue NEXT row's loads first: serviced under this row's compute ----
    int4 attnN[CPW]; float4 wN[CPW]; int4 idsN[CPW];
    if (rr < DSEQ - 1) {
      const size_t rbN = rbase + SLEN;
      const int4*   av4 = (const int4*)(attn + rbN);
      const float4* wv4 = (const float4*)(wfull + 2 * rbN);
      const int4*   iv4 = (const int4*)(ids + rbN);
#pragma unroll
      for (int j = 0; j < CPW; ++j) {
        attnN[j] = av4[64 * (CPW * wl + j) + lane];
        wN[j]    = wv4[64 * (CPW * wl + j) + lane];
        idsN[j]  = iv4[64 * (CPW * wl + j) + lane];
      }
    }

    // zero my half of my pair's hist buffer 0
    ((uint2*)hist[pid][0])[64 * wl + lane] = make_uint2(0u, 0u);

    // ---- attention sum from prefetched regs ----
    int psum = 0;
#pragma unroll
    for (int j = 0; j < CPW; ++j)
      psum += attnC[j].x + attnC[j].y + attnC[j].z + attnC[j].w;

    // ---- frac (redundant per wave; long f64 chain) ----
    uint32_t no0, no1;
    tf2x32(kn0, kn1, 0u, (uint32_t)row, no0, no1);
    float f0  = u01_from_bits(no0 ^ no1);
    float lo  = __uint_as_float(0xBF7FFFFFu);        // nextafter(-1,0)
    float u2  = fmaxf(lo, f0 * 2.0f + lo);           // (1-lo) rounds to 2.0f
    float z   = erfinv_xla(u2);
    float nrm = 1.4142135623730951f * z;
    float frac = 0.15f + 0.0375f * nrm;

#pragma unroll
    for (int off = 32; off; off >>= 1) psum += __shfl_down(psum, off, 64);
    if (lane == 0) wsum[pid][wl] = (uint32_t)psum;

    // ---- key pipeline: 2 chunk-pairs x 8 elements (forced-ILP) ----
    uint32_t mloc[EPT];
#pragma unroll
    for (int c = 0; c < 2; ++c) {
      const int g0 = CPW * wl + 2 * c;
      float4 wa = wC[2 * c], wb = wC[2 * c + 1];
      uint32_t bits[8];
      tf4_bits(kg0, kg1, (uint32_t)(rbase + 256 * g0 + 4 * lane), bits + 0);
      tf4_bits(kg0, kg1, (uint32_t)(rbase + 256 * (g0 + 1) + 4 * lane), bits + 4);
      SBAR();
      float wl8[8] = {wa.x, wa.y, wa.z, wa.w, wb.x, wb.y, wb.z, wb.w};
      float uu[8];
#pragma unroll
      for (int e = 0; e < 8; ++e) {
        float f = u01_from_bits(bits[e]);
        uu[e] = fmaxf(1.17549435e-38f, f * 1.0f + 1.17549435e-38f);
      }
      SBAR();
      float l1[8];
      log8_cr(uu, l1);                       // log u
      float wm[8];
#pragma unroll
      for (int e = 0; e < 8; ++e) wm[e] = fmaxf(wl8[e], 1e-30f);
      float lw[8];
      log8_cr(wm, lw);                       // log w
      float nl1[8];
#pragma unroll
      for (int e = 0; e < 8; ++e) nl1[e] = -l1[e];
      float l2[8];
      log8_cr(nl1, l2);                      // log(-log u); gumbel = -l2
      SBAR();
#pragma unroll
      for (int e = 0; e < 8; ++e) {
        float key = (wl8[e] > 0.0f) ? (lw[e] + (-l2[e])) : -__builtin_inff();
        uint32_t kb = __float_as_uint(key);
        mloc[8 * c + e] = (kb & 0x80000000u) ? ~kb : (kb | 0x80000000u);  // monotone
      }
    }

    __syncthreads();                 // B1: hist zeros + wsum visible
    int asum = (int)(wsum[pid][0] + wsum[pid][1]);
    int kk = (int)floorf((float)asum * frac);

    // ---- radix-select, UNIFORM 4 passes (barrier-safe across pairs) ----
    uint32_t T = 0u, r = 0u, need = 0u;
    bool doneF = false;
    if (kk <= 0)          { T = 0xFFFFFFFFu; r = 0u; doneF = true; }
    else if (kk >= SLEN)  { T = 0u; r = (uint32_t)SLEN; doneF = true; }
    else {
      need = (uint32_t)kk;
#pragma unroll
      for (int e = 0; e < EPT; ++e)
        atomicAdd(&hist[pid][0][mloc[e] >> 24], 1u);
    }
    int cur = 0;
    for (int p = 3; p >= 0; --p) {
      __syncthreads();                                 // pass-p atomics done
      if (!doneF) {
        uint4 hq = ((const uint4*)hist[pid][cur])[lane];
        ((uint2*)hist[pid][cur ^ 1])[64 * wl + lane] = make_uint2(0u, 0u);
        uint32_t gs  = hq.x + hq.y + hq.z + hq.w;
        uint32_t sfx = gs;                             // inclusive suffix sum
#pragma unroll
        for (int off = 1; off < 64; off <<= 1) {
          uint32_t n = __shfl_down(sfx, off, 64);
          if (lane + off < 64) sfx += n;
        }
        uint32_t Gex = sfx - gs;                       // sum over lanes > me
        uint32_t S3 = Gex;
        uint32_t S2 = S3 + hq.w;
        uint32_t S1 = S2 + hq.z;
        uint32_t S0 = S1 + hq.y;
        uint32_t hh[4] = {hq.x, hq.y, hq.z, hq.w};
        uint32_t SS[4] = {S0, S1, S2, S3};
        int haswin = 0; uint32_t binv = 0u, remv = 0u; int donev = 0;
#pragma unroll
        for (int i = 0; i < 4; ++i) {
          if (hh[i] && SS[i] < need && need <= SS[i] + hh[i]) {   // unique winner
            haswin = 1;
            binv = (uint32_t)(4 * lane + i);
            remv = need - SS[i];
            donev = (remv == hh[i]) ? 1 : 0;   // whole bin: low bytes stay 0
          }
        }
        unsigned long long wmask = __ballot(haswin);
        int src = (int)(__ffsll((unsigned long long)wmask) - 1);
        uint32_t bin = (uint32_t)__shfl((int)binv, src, 64);
        uint32_t rem = (uint32_t)__shfl((int)remv, src, 64);
        int     done = __shfl(donev, src, 64);
        T |= bin << (8 * p);
        need = rem;
        if (done || p == 0) { r = rem; doneF = true; }
      }
      __syncthreads();                                 // reads + clears done
      if (!doneF && p > 0) {
        const int sh = 8 * p;
#pragma unroll
        for (int e = 0; e < EPT; ++e) {
          uint32_t m = mloc[e];
          if ((m >> sh) == (T >> sh))
            atomicAdd(&hist[pid][cur ^ 1][(m >> (sh - 8)) & 255u], 1u);
        }
      }
      cur ^= 1;
    }

    // ---- stable tie-break in INDEX order (within wave, then across) ----
    uint32_t cnt[CPW];
#pragma unroll
    for (int j = 0; j < CPW; ++j) {
      uint32_t c = 0;
#pragma unroll
      for (int e = 0; e < 4; ++e) c += (mloc[4 * j + e] == T) ? 1u : 0u;
      cnt[j] = c;
    }
    uint32_t incl[2];
#pragma unroll
    for (int q = 0; q < 2; ++q) incl[q] = cnt[2 * q] | (cnt[2 * q + 1] << 16);
#pragma unroll
    for (int off = 1; off < 64; off <<= 1) {
#pragma unroll
      for (int q = 0; q < 2; ++q) {
        uint32_t n = __shfl_up(incl[q], off, 64);
        if (lane >= off) incl[q] += n;
      }
    }
    uint32_t Spre[CPW], tot[CPW];
#pragma unroll
    for (int q = 0; q < 2; ++q) {
      uint32_t t63 = (uint32_t)__shfl((int)incl[q], 63, 64);
      tot[2 * q]      = t63 & 0xFFFFu;
      tot[2 * q + 1]  = t63 >> 16;
      Spre[2 * q]     = (incl[q] & 0xFFFFu) - cnt[2 * q];
      Spre[2 * q + 1] = (incl[q] >> 16)     - cnt[2 * q + 1];
    }
    if (lane == 0) wtot[pid][wl] = tot[0] + tot[1] + tot[2] + tot[3];
    __syncthreads();
    uint32_t C = wl ? wtot[pid][0] : 0u;   // eq-count in earlier half

    // ---- epilogue: masked writes (coalesced, fire-and-forget) ----
    int4* po = (int4*)(out + rbase);
    int4* pm = (int4*)(out + TOKENS_PER_OUT + rbase);
    int4* pl = (int4*)(out + 2 * TOKENS_PER_OUT + rbase);
#pragma unroll
    for (int j = 0; j < CPW; ++j) {
      uint32_t excl = C + Spre[j];
      int4 iv = idsC[j];
      int idv[4] = {iv.x, iv.y, iv.z, iv.w};
      int oid[4], omk[4], olb[4];
#pragma unroll
      for (int e = 0; e < 4; ++e) {
        uint32_t m = mloc[4 * j + e];
        bool eq  = (m == T);
        bool msk = (m > T) || (eq && (excl < r));
        excl += eq ? 1u : 0u;
        oid[e] = msk ? 103 : idv[e];      // MASK_ID
        omk[e] = msk ? 1 : 0;
        olb[e] = msk ? -1 : 0;
      }
      const int gi = 64 * (CPW * wl + j) + lane;
      po[gi] = make_int4(oid[0], oid[1], oid[2], oid[3]);
      pm[gi] = make_int4(omk[0], omk[1], omk[2], omk[3]);
      pl[gi] = make_int4(olb[0], olb[1], olb[2], olb[3]);
      C += tot[j];
    }

    // ---- rotate pipeline registers ----
    if (rr < DSEQ - 1) {
#pragma unroll
      for (int j = 0; j < CPW; ++j) {
        attnC[j] = attnN[j];
        wC[j]    = wN[j];
        idsC[j]  = idsN[j];
      }
    }
  }
}

extern "C" void kernel_launch(void* const* d_in, const int* in_sizes, int n_in,
                              void* d_out, int out_size, void* d_ws, size_t ws_size,
                              hipStream_t stream) {
  (void)n_in; (void)d_ws; (void)ws_size; (void)out_size;
  const float* wfull = (const float*)d_in[0];   // my_attention_mask (B,C,2S)
  const int*   attn  = (const int*)d_in[1];     // attention_mask    (B,C,S)
  const int*   ids   = (const int*)d_in[2];     // input_ids         (B,C,S)
  int* out = (int*)d_out;

  // jax.random.key(42) -> (0,42); partitionable split: kg=enc(key,(0,0)), kn=enc(key,(0,1))
  uint32_t kg0, kg1, kn0, kn1, o0, o1;
  tf2x32(0u, 42u, 0u, 0u, o0, o1); kg0 = o0; kg1 = o1;
  tf2x32(0u, 42u, 0u, 1u, o0, o1); kn0 = o0; kn1 = o1;

  int rows = in_sizes[1] / SLEN;                // 4096
  hipLaunchKernelGGL(gumbel_topk_mask, dim3(rows / (2 * DSEQ)), dim3(NTHREADS),
                     0, stream, wfull, attn, ids, out, kg0, kg1, kn0, kn1);
}

// Round 7
// 202.907 us; speedup vs baseline: 1.1679x; 1.1679x over previous
//
#include <hip/hip_runtime.h>
#include <stdint.h>
#include <math.h>

#define SLEN 2048
#define EPT 16               // elements per lane: half a row per wave
#define NTHREADS 128         // 2 waves = 1 row per block
#define CPW 4                // chunks (of 256 el) per wave; row = 8 chunks
#define TOKENS_PER_OUT 8388608   // 1024*4*2048

// ---------- Threefry-2x32, 20 rounds, matches jax._src.prng ----------
__host__ __device__ __forceinline__ void tf2x32(uint32_t k0, uint32_t k1,
                                                uint32_t x0, uint32_t x1,
                                                uint32_t &o0, uint32_t &o1) {
  uint32_t ks2 = 0x1BD11BDAu ^ k0 ^ k1;
  x0 += k0; x1 += k1;
#define TFR(r) { x0 += x1; x1 = (x1 << (r)) | (x1 >> (32 - (r))); x1 ^= x0; }
  TFR(13) TFR(15) TFR(26) TFR(6)
  x0 += k1;  x1 += ks2 + 1u;
  TFR(17) TFR(29) TFR(16) TFR(24)
  x0 += ks2; x1 += k0 + 2u;
  TFR(13) TFR(15) TFR(26) TFR(6)
  x0 += k0;  x1 += k1 + 3u;
  TFR(17) TFR(29) TFR(16) TFR(24)
  x0 += k1;  x1 += ks2 + 4u;
  TFR(13) TFR(15) TFR(26) TFR(6)
  x0 += ks2; x1 += k0 + 5u;
#undef TFR
  o0 = x0; o1 = x1;
}

// 4 independent threefry streams; sched_barrier after each round keeps the
// 4-wide interleave intact through the machine scheduler.
__device__ __forceinline__ void tf4_bits(uint32_t k0, uint32_t k1,
                                         uint32_t cbase, uint32_t bits[4]) {
  const uint32_t ks2 = 0x1BD11BDAu ^ k0 ^ k1;
  uint32_t x0[4], x1[4];
#pragma unroll
  for (int i = 0; i < 4; ++i) { x0[i] = k0; x1[i] = (cbase + (uint32_t)i) + k1; }
#define TFR4(r)                                                         \
  _Pragma("unroll")                                                     \
  for (int i = 0; i < 4; ++i) {                                         \
    x0[i] += x1[i];                                                     \
    x1[i] = (x1[i] << (r)) | (x1[i] >> (32 - (r)));                     \
    x1[i] ^= x0[i];                                                     \
  }                                                                     \
  __builtin_amdgcn_sched_barrier(0);
#define INJ4(a, b)                                                      \
  _Pragma("unroll")                                                     \
  for (int i = 0; i < 4; ++i) { x0[i] += (a); x1[i] += (b); }
  TFR4(13) TFR4(15) TFR4(26) TFR4(6)
  INJ4(k1, ks2 + 1u)
  TFR4(17) TFR4(29) TFR4(16) TFR4(24)
  INJ4(ks2, k0 + 2u)
  TFR4(13) TFR4(15) TFR4(26) TFR4(6)
  INJ4(k0, k1 + 3u)
  TFR4(17) TFR4(29) TFR4(16) TFR4(24)
  INJ4(k1, ks2 + 4u)
  TFR4(13) TFR4(15) TFR4(26) TFR4(6)
  INJ4(ks2, k0 + 5u)
#undef TFR4
#undef INJ4
#pragma unroll
  for (int i = 0; i < 4; ++i) bits[i] = x0[i] ^ x1[i];
}

__device__ __forceinline__ float u01_from_bits(uint32_t bits) {
  return __uint_as_float((bits >> 9) | 0x3F800000u) - 1.0f;
}

#define SBAR() __builtin_amdgcn_sched_barrier(0)

// ---- DPP wave64 scan primitives (replaces ds_bpermute shuffles: ~2cy VALU
// latency per step instead of ~30-40cy DS latency per step) ----
template<int CTRL, int RMASK>
__device__ __forceinline__ uint32_t dpp_mov0(uint32_t x) {
  // invalid/masked lanes yield 0 (old=0, bound_ctrl=false)
  return (uint32_t)__builtin_amdgcn_update_dpp(0, (int)x, CTRL, RMASK, 0xF, false);
}
// classic GCN wave64 inclusive prefix sum: row_shr 1/2/4/8, bcast15->rows 1,3,
// bcast31->rows 2,3
__device__ __forceinline__ uint32_t wave_incl_scan(uint32_t x) {
  x += dpp_mov0<0x111, 0xF>(x);   // row_shr:1
  x += dpp_mov0<0x112, 0xF>(x);   // row_shr:2
  x += dpp_mov0<0x114, 0xF>(x);   // row_shr:4
  x += dpp_mov0<0x118, 0xF>(x);   // row_shr:8
  x += dpp_mov0<0x142, 0xA>(x);   // row_bcast:15 into rows 1,3
  x += dpp_mov0<0x143, 0xC>(x);   // row_bcast:31 into rows 2,3
  return x;
}

// 8 correctly-rounded-quality f32 logs (positive normal f32 inputs), staged
// 8-wide with hard sched barriers so dependent f64 ops sit ~8 instrs apart.
// Bit-identical to the verified scalar math:
//   x = 2^e * m, m in [sqrt2/2, sqrt2), r = (m-1)*rcp(m+1) w/ 1 Newton,
//   log = e*ln2 + 2r*(1 + t/3 + .. + t^6/13).
__device__ __forceinline__ void log8_cr(const float x[8], float out[8]) {
#pragma clang fp contract(off)
  double m[8]; int e[8];
#pragma unroll
  for (int i = 0; i < 8; ++i) {
    uint32_t xb   = __float_as_uint(x[i]);
    uint32_t mant = xb & 0x7FFFFFu;
    int      ee   = (int)(xb >> 23) - 127;
    bool     big  = mant > 0x3504F3u;          // m > sqrt(2)
    e[i] = ee + (big ? 1 : 0);
    uint32_t hi = (big ? 0x3FE00000u : 0x3FF00000u) | (mant >> 3);
    uint32_t lo = mant << 29;
    m[i] = __longlong_as_double(((long long)hi << 32) | (long long)lo);
  }
  SBAR();
  double mp1[8];
#pragma unroll
  for (int i = 0; i < 8; ++i) mp1[i] = m[i] + 1.0;
  SBAR();
  double y[8];
#pragma unroll
  for (int i = 0; i < 8; ++i) y[i] = __builtin_amdgcn_rcp(mp1[i]);
  SBAR();
#pragma unroll
  for (int i = 0; i < 8; ++i) y[i] = fma(fma(-mp1[i], y[i], 1.0), y[i], y[i]);
  SBAR();
  double r[8];
#pragma unroll
  for (int i = 0; i < 8; ++i) r[i] = (m[i] - 1.0) * y[i];
  SBAR();
  double t[8];
#pragma unroll
  for (int i = 0; i < 8; ++i) t[i] = r[i] * r[i];
  SBAR();
  double p[8];
#pragma unroll
  for (int i = 0; i < 8; ++i) p[i] = fma(0.07692307692307693, t[i], 0.09090909090909091);
  SBAR();
#pragma unroll
  for (int i = 0; i < 8; ++i) p[i] = fma(p[i], t[i], 0.1111111111111111);
  SBAR();
#pragma unroll
  for (int i = 0; i < 8; ++i) p[i] = fma(p[i], t[i], 0.14285714285714285);
  SBAR();
#pragma unroll
  for (int i = 0; i < 8; ++i) p[i] = fma(p[i], t[i], 0.2);
  SBAR();
#pragma unroll
  for (int i = 0; i < 8; ++i) p[i] = fma(p[i], t[i], 0.3333333333333333);
  SBAR();
#pragma unroll
  for (int i = 0; i < 8; ++i) p[i] = fma(p[i], t[i], 1.0);
  SBAR();
#pragma unroll
  for (int i = 0; i < 8; ++i) r[i] = r[i] + r[i];       // 2r (exact)
  SBAR();
#pragma unroll
  for (int i = 0; i < 8; ++i) p[i] = r[i] * p[i];       // 2r*q
  SBAR();
#pragma unroll
  for (int i = 0; i < 8; ++i)
    out[i] = (float)fma((double)e[i], 0.6931471805599453, p[i]);
}

// scalar CR log (erfinv path only; same math, unstaged)
__device__ __forceinline__ float log_cr(float x) {
#pragma clang fp contract(off)
  uint32_t xb   = __float_as_uint(x);
  uint32_t mant = xb & 0x7FFFFFu;
  int      e    = (int)(xb >> 23) - 127;
  bool     big  = mant > 0x3504F3u;
  e += big ? 1 : 0;
  uint32_t hi = (big ? 0x3FE00000u : 0x3FF00000u) | (mant >> 3);
  double m = __longlong_as_double(((long long)hi << 32) | (long long)(mant << 29));
  double mp1 = m + 1.0;
  double y = __builtin_amdgcn_rcp(mp1);
  y = fma(fma(-mp1, y, 1.0), y, y);
  double r = (m - 1.0) * y;
  double t = r * r;
  double p = fma(0.07692307692307693, t, 0.09090909090909091);
  p = fma(p, t, 0.1111111111111111);
  p = fma(p, t, 0.14285714285714285);
  p = fma(p, t, 0.2);
  p = fma(p, t, 0.3333333333333333);
  p = fma(p, t, 1.0);
  return (float)fma((double)e, 0.6931471805599453, (r + r) * p);
}

// XLA ErfInv f32 expander (Giles poly), log1p per ElementalIrEmitter::EmitLog1p
__device__ float erfinv_xla(float x) {
#pragma clang fp contract(off)
  float x2  = x * x;
  float nx2 = -x2;
  float l1p;
  if (fabsf(nx2) < 1e-4f) {
    l1p = (-0.5f * nx2 + 1.0f) * nx2;
  } else {
    l1p = log_cr(1.0f + nx2);
  }
  float w = -l1p;
  float p;
  if (w < 5.0f) {
    float ww = w - 2.5f;
    p = 2.81022636e-08f;
    p = p * ww + 3.43273939e-07f;
    p = p * ww + -3.5233877e-06f;
    p = p * ww + -4.39150654e-06f;
    p = p * ww + 0.00021858087f;
    p = p * ww + -0.00125372503f;
    p = p * ww + -0.00417768164f;
    p = p * ww + 0.246640727f;
    p = p * ww + 1.50140941f;
  } else {
    float ww = sqrtf(w) - 3.0f;
    p = -0.000200214257f;
    p = p * ww + 0.000100950558f;
    p = p * ww + 0.00134934322f;
    p = p * ww + -0.00367342844f;
    p = p * ww + 0.00573950773f;
    p = p * ww + -0.0076224613f;
    p = p * ww + 0.00943887047f;
    p = p * ww + 1.00167406f;
    p = p * ww + 2.83297682f;
  }
  return p * x;
}

// R7 = R4 (best TLP config: 2 waves/row, grid 4096, 128-thr blocks) + latency
// cuts. R6 proved the ~36us non-VALU time is NOT un-prefetched HBM (full
// prefetch at 2 waves/SIMD still stalled 58us) -- it's the select phase's
// dependent-op latency: ~50 ds_bpermute-based shuffle steps/row at ~30-40cy
// each. Fix: (1) DPP-based wave64 scans (VALU, ~2cy/step) for radix suffix
// scans, tie-break scan, psum reduce; (2) v_readlane broadcasts instead of
// __shfl(x,src); (3) w-loads hoisted to kernel top (consumed ~5k cy later).
// launch_bounds(128,7): budget 73 VGPR for the +16 hoisted regs.
__global__ __launch_bounds__(NTHREADS, 7)
void gumbel_topk_mask(const float* __restrict__ wfull,   // (B,C,2S) f32
                      const int*   __restrict__ attn,    // (B,C,S) i32
                      const int*   __restrict__ ids,     // (B,C,S) i32
                      int* __restrict__ out,             // 3x(B,C,S) i32 concat
                      uint32_t kg0, uint32_t kg1, uint32_t kn0, uint32_t kn1) {
#pragma clang fp contract(off)
  const int t    = threadIdx.x;
  const int lane = t & 63;
  const int wid  = t >> 6;            // 0 or 1: which half-row
  const int row  = blockIdx.x;

  __shared__ __align__(16) uint32_t hist[2][256];
  __shared__ uint32_t wsum[2];
  __shared__ uint32_t wtot[2];

  const size_t rbase = (size_t)row * SLEN;
  const size_t wbase = (size_t)row * (2 * SLEN);

  // zero my half of hist buffer 0 (buffer 1 cleared in pass 3's window)
  ((uint2*)hist[0])[64 * wid + lane] = make_uint2(0u, 0u);

  const int4*   av4 = (const int4*)(attn + rbase);
  const float4* wv4 = (const float4*)(wfull + wbase);
  const int4*   iv4 = (const int4*)(ids + rbase);

  // ---- attention + weight loads issued up front (coalesced); w consumed
  // ~5k cycles later under the threefry/f64 pipeline ----
  int psum = 0;
#pragma unroll
  for (int j = 0; j < CPW; ++j) {
    int4 a = av4[64 * (CPW * wid + j) + lane];
    psum += a.x + a.y + a.z + a.w;
  }
  float4 wC[CPW];
#pragma unroll
  for (int j = 0; j < CPW; ++j) wC[j] = wv4[64 * (CPW * wid + j) + lane];

  // ---- frac (redundant per wave; long f64 chain hides load latency) ----
  uint32_t no0, no1;
  tf2x32(kn0, kn1, 0u, (uint32_t)row, no0, no1);
  float f0  = u01_from_bits(no0 ^ no1);
  float lo  = __uint_as_float(0xBF7FFFFFu);        // nextafter(-1,0)
  float u2  = fmaxf(lo, f0 * 2.0f + lo);           // (1-lo) rounds to 2.0f
  float z   = erfinv_xla(u2);
  float nrm = 1.4142135623730951f * z;
  float frac = 0.15f + 0.0375f * nrm;

  // ---- half-row attention sum: DPP scan + readlane(63) -> LDS ----
  {
    uint32_t ps = wave_incl_scan((uint32_t)psum);
    if (lane == 63) wsum[wid] = ps;       // lane63 holds the wave total
  }

  // ---- key pipeline: 2 chunk-pairs x 8 elements (forced-ILP) ----
  uint32_t mloc[EPT];
#pragma unroll
  for (int c = 0; c < 2; ++c) {
    const int g0 = CPW * wid + 2 * c;
    float4 wa = wC[2 * c];
    float4 wb = wC[2 * c + 1];
    uint32_t bits[8];
    tf4_bits(kg0, kg1, (uint32_t)(rbase + 256 * g0 + 4 * lane), bits + 0);
    tf4_bits(kg0, kg1, (uint32_t)(rbase + 256 * (g0 + 1) + 4 * lane), bits + 4);
    SBAR();
    float wl8[8] = {wa.x, wa.y, wa.z, wa.w, wb.x, wb.y, wb.z, wb.w};
    float uu[8];
#pragma unroll
    for (int e = 0; e < 8; ++e) {
      float f = u01_from_bits(bits[e]);
      uu[e] = fmaxf(1.17549435e-38f, f * 1.0f + 1.17549435e-38f);
    }
    SBAR();
    float l1[8];
    log8_cr(uu, l1);                       // log u
    float wm[8];
#pragma unroll
    for (int e = 0; e < 8; ++e) wm[e] = fmaxf(wl8[e], 1e-30f);
    float lw[8];
    log8_cr(wm, lw);                       // log w
    float nl1[8];
#pragma unroll
    for (int e = 0; e < 8; ++e) nl1[e] = -l1[e];
    float l2[8];
    log8_cr(nl1, l2);                      // log(-log u); gumbel = -l2
    SBAR();
#pragma unroll
    for (int e = 0; e < 8; ++e) {
      float key = (wl8[e] > 0.0f) ? (lw[e] + (-l2[e])) : -__builtin_inff();
      uint32_t kb = __float_as_uint(key);
      mloc[8 * c + e] = (kb & 0x80000000u) ? ~kb : (kb | 0x80000000u);  // monotone
    }
  }

  // ids loads: issue now, consumed in epilogue (hidden under the select)
  int4 idsv[CPW];
#pragma unroll
  for (int j = 0; j < CPW; ++j) idsv[j] = iv4[64 * (CPW * wid + j) + lane];

  __syncthreads();                 // hist[0] zeros + wsum visible block-wide
  int asum = (int)(wsum[0] + wsum[1]);
  int kk = (int)floorf((float)asum * frac);

  // ---- block-shared radix-select of the k-th largest key ----
  uint32_t T, r;
  if (kk <= 0)          { T = 0xFFFFFFFFu; r = 0u; }             // mask nothing
  else if (kk >= SLEN)  { T = 0u;          r = (uint32_t)SLEN; } // mask all
  else {
    T = 0u;
    uint32_t need = (uint32_t)kk;
#pragma unroll
    for (int e = 0; e < EPT; ++e)
      atomicAdd(&hist[0][mloc[e] >> 24], 1u);
    int cur = 0;
    for (int p = 3; ; --p) {
      __syncthreads();                                   // pass-p atomics done
      uint4 hq = ((const uint4*)hist[cur])[lane];        // bins 4*lane..+3
      ((uint2*)hist[cur ^ 1])[64 * wid + lane] = make_uint2(0u, 0u);  // clear other
      uint32_t gs = hq.x + hq.y + hq.z + hq.w;
      // DPP inclusive prefix -> Gex = total - P (sum over lanes > me)
      uint32_t P     = wave_incl_scan(gs);
      uint32_t total = (uint32_t)__builtin_amdgcn_readlane((int)P, 63);
      uint32_t Gex   = total - P;
      uint32_t S3 = Gex;
      uint32_t S2 = S3 + hq.w;
      uint32_t S1 = S2 + hq.z;
      uint32_t S0 = S1 + hq.y;
      uint32_t hh[4] = {hq.x, hq.y, hq.z, hq.w};
      uint32_t SS[4] = {S0, S1, S2, S3};
      int haswin = 0; uint32_t binv = 0u, remv = 0u; int donev = 0;
#pragma unroll
      for (int i = 0; i < 4; ++i) {
        if (hh[i] && SS[i] < need && need <= SS[i] + hh[i]) {   // unique winner
          haswin = 1;
          binv = (uint32_t)(4 * lane + i);
          remv = need - SS[i];
          donev = (remv == hh[i]) ? 1 : 0;   // whole bin taken: low bytes stay 0
        }
      }
      unsigned long long wmask = __ballot(haswin);
      int src = (int)(__ffsll((unsigned long long)wmask) - 1);
      uint32_t bin = (uint32_t)__builtin_amdgcn_readlane((int)binv, src);
      uint32_t rem = (uint32_t)__builtin_amdgcn_readlane((int)remv, src);
      int     done = __builtin_amdgcn_readlane(donev, src);
      T |= bin << (8 * p);
      need = rem;
      if (done || p == 0) { r = rem; break; }            // uniform block-wide
      __syncthreads();                                   // reads + clears done
      const int sh = 8 * p;
#pragma unroll
      for (int e = 0; e < EPT; ++e) {
        uint32_t m = mloc[e];
        if ((m >> sh) == (T >> sh))
          atomicAdd(&hist[cur ^ 1][(m >> (sh - 8)) & 255u], 1u);
      }
      cur ^= 1;
    }
  }

  // ---- stable tie-break in INDEX order (DPP packed scan; lane chunks are
  // index-contiguous within each 256-el chunk) ----
  uint32_t cnt[CPW];
#pragma unroll
  for (int j = 0; j < CPW; ++j) {
    uint32_t c = 0;
#pragma unroll
    for (int e = 0; e < 4; ++e) c += (mloc[4 * j + e] == T) ? 1u : 0u;
    cnt[j] = c;
  }
  uint32_t incl[2];
#pragma unroll
  for (int q = 0; q < 2; ++q)
    incl[q] = wave_incl_scan(cnt[2 * q] | (cnt[2 * q + 1] << 16));
  uint32_t Spre[CPW], tot[CPW];
#pragma unroll
  for (int q = 0; q < 2; ++q) {
    uint32_t t63 = (uint32_t)__builtin_amdgcn_readlane((int)incl[q], 63);
    tot[2 * q]      = t63 & 0xFFFFu;
    tot[2 * q + 1]  = t63 >> 16;
    Spre[2 * q]     = (incl[q] & 0xFFFFu) - cnt[2 * q];
    Spre[2 * q + 1] = (incl[q] >> 16)     - cnt[2 * q + 1];
  }
  if (lane == 0) wtot[wid] = tot[0] + tot[1] + tot[2] + tot[3];
  __syncthreads();
  uint32_t C = wid ? wtot[0] : 0u;   // eq-count in the other wave's earlier half

  // ---- epilogue: masked writes (coalesced, fire-and-forget) ----
  int4* po = (int4*)(out + rbase);
  int4* pm = (int4*)(out + TOKENS_PER_OUT + rbase);
  int4* pl = (int4*)(out + 2 * TOKENS_PER_OUT + rbase);
#pragma unroll
  for (int j = 0; j < CPW; ++j) {
    uint32_t excl = C + Spre[j];
    int4 iv = idsv[j];
    int idv[4] = {iv.x, iv.y, iv.z, iv.w};
    int oid[4], omk[4], olb[4];
#pragma unroll
    for (int e = 0; e < 4; ++e) {
      uint32_t m = mloc[4 * j + e];
      bool eq  = (m == T);
      bool msk = (m > T) || (eq && (excl < r));
      excl += eq ? 1u : 0u;
      oid[e] = msk ? 103 : idv[e];      // MASK_ID
      omk[e] = msk ? 1 : 0;
      olb[e] = msk ? -1 : 0;
    }
    const int gi = 64 * (CPW * wid + j) + lane;
    po[gi] = make_int4(oid[0], oid[1], oid[2], oid[3]);
    pm[gi] = make_int4(omk[0], omk[1], omk[2], omk[3]);
    pl[gi] = make_int4(olb[0], olb[1], olb[2], olb[3]);
    C += tot[j];
  }
}

extern "C" void kernel_launch(void* const* d_in, const int* in_sizes, int n_in,
                              void* d_out, int out_size, void* d_ws, size_t ws_size,
                              hipStream_t stream) {
  (void)n_in; (void)d_ws; (void)ws_size; (void)out_size;
  const float* wfull = (const float*)d_in[0];   // my_attention_mask (B,C,2S)
  const int*   attn  = (const int*)d_in[1];     // attention_mask    (B,C,S)
  const int*   ids   = (const int*)d_in[2];     // input_ids         (B,C,S)
  int* out = (int*)d_out;

  // jax.random.key(42) -> (0,42); partitionable split: kg=enc(key,(0,0)), kn=enc(key,(0,1))
  uint32_t kg0, kg1, kn0, kn1, o0, o1;
  tf2x32(0u, 42u, 0u, 0u, o0, o1); kg0 = o0; kg1 = o1;
  tf2x32(0u, 42u, 0u, 1u, o0, o1); kn0 = o0; kn1 = o1;

  int rows = in_sizes[1] / SLEN;                // 4096
  hipLaunchKernelGGL(gumbel_topk_mask, dim3(rows), dim3(NTHREADS),
                     0, stream, wfull, attn, ids, out, kg0, kg1, kn0, kn1);
}

// Round 8
// 202.264 us; speedup vs baseline: 1.1716x; 1.0032x over previous
//
#include <hip/hip_runtime.h>
#include <stdint.h>
#include <math.h>

#define SLEN 2048
#define EPT 16               // elements per lane: half a row per wave
#define NTHREADS 128         // 2 waves = 1 row per block
#define CPW 4                // chunks (of 256 el) per wave; row = 8 chunks
#define TOKENS_PER_OUT 8388608   // 1024*4*2048

// ---------- Threefry-2x32, 20 rounds, matches jax._src.prng ----------
__host__ __device__ __forceinline__ void tf2x32(uint32_t k0, uint32_t k1,
                                                uint32_t x0, uint32_t x1,
                                                uint32_t &o0, uint32_t &o1) {
  uint32_t ks2 = 0x1BD11BDAu ^ k0 ^ k1;
  x0 += k0; x1 += k1;
#define TFR(r) { x0 += x1; x1 = (x1 << (r)) | (x1 >> (32 - (r))); x1 ^= x0; }
  TFR(13) TFR(15) TFR(26) TFR(6)
  x0 += k1;  x1 += ks2 + 1u;
  TFR(17) TFR(29) TFR(16) TFR(24)
  x0 += ks2; x1 += k0 + 2u;
  TFR(13) TFR(15) TFR(26) TFR(6)
  x0 += k0;  x1 += k1 + 3u;
  TFR(17) TFR(29) TFR(16) TFR(24)
  x0 += k1;  x1 += ks2 + 4u;
  TFR(13) TFR(15) TFR(26) TFR(6)
  x0 += ks2; x1 += k0 + 5u;
#undef TFR
  o0 = x0; o1 = x1;
}

// 4 independent threefry streams; sched_barrier after each round keeps the
// 4-wide interleave intact through the machine scheduler.
__device__ __forceinline__ void tf4_bits(uint32_t k0, uint32_t k1,
                                         uint32_t cbase, uint32_t bits[4]) {
  const uint32_t ks2 = 0x1BD11BDAu ^ k0 ^ k1;
  uint32_t x0[4], x1[4];
#pragma unroll
  for (int i = 0; i < 4; ++i) { x0[i] = k0; x1[i] = (cbase + (uint32_t)i) + k1; }
#define TFR4(r)                                                         \
  _Pragma("unroll")                                                     \
  for (int i = 0; i < 4; ++i) {                                         \
    x0[i] += x1[i];                                                     \
    x1[i] = (x1[i] << (r)) | (x1[i] >> (32 - (r)));                     \
    x1[i] ^= x0[i];                                                     \
  }                                                                     \
  __builtin_amdgcn_sched_barrier(0);
#define INJ4(a, b)                                                      \
  _Pragma("unroll")                                                     \
  for (int i = 0; i < 4; ++i) { x0[i] += (a); x1[i] += (b); }
  TFR4(13) TFR4(15) TFR4(26) TFR4(6)
  INJ4(k1, ks2 + 1u)
  TFR4(17) TFR4(29) TFR4(16) TFR4(24)
  INJ4(ks2, k0 + 2u)
  TFR4(13) TFR4(15) TFR4(26) TFR4(6)
  INJ4(k0, k1 + 3u)
  TFR4(17) TFR4(29) TFR4(16) TFR4(24)
  INJ4(k1, ks2 + 4u)
  TFR4(13) TFR4(15) TFR4(26) TFR4(6)
  INJ4(ks2, k0 + 5u)
#undef TFR4
#undef INJ4
#pragma unroll
  for (int i = 0; i < 4; ++i) bits[i] = x0[i] ^ x1[i];
}

__device__ __forceinline__ float u01_from_bits(uint32_t bits) {
  return __uint_as_float((bits >> 9) | 0x3F800000u) - 1.0f;
}

#define SBAR() __builtin_amdgcn_sched_barrier(0)

// ---- DPP wave64 scan primitives (VALU ~2cy/step vs ds_bpermute ~30-40cy) ----
template<int CTRL, int RMASK>
__device__ __forceinline__ uint32_t dpp_mov0(uint32_t x) {
  // invalid/masked lanes yield 0 (old=0, bound_ctrl=false)
  return (uint32_t)__builtin_amdgcn_update_dpp(0, (int)x, CTRL, RMASK, 0xF, false);
}
// classic GCN wave64 inclusive prefix sum: row_shr 1/2/4/8, bcast15->rows 1,3,
// bcast31->rows 2,3
__device__ __forceinline__ uint32_t wave_incl_scan(uint32_t x) {
  x += dpp_mov0<0x111, 0xF>(x);   // row_shr:1
  x += dpp_mov0<0x112, 0xF>(x);   // row_shr:2
  x += dpp_mov0<0x114, 0xF>(x);   // row_shr:4
  x += dpp_mov0<0x118, 0xF>(x);   // row_shr:8
  x += dpp_mov0<0x142, 0xA>(x);   // row_bcast:15 into rows 1,3
  x += dpp_mov0<0x143, 0xC>(x);   // row_bcast:31 into rows 2,3
  return x;
}

// 8 correctly-rounded-quality f32 logs (positive normal f32 inputs), staged
// 8-wide with hard sched barriers so dependent f64 ops sit ~8 instrs apart.
// Bit-identical to the verified scalar math:
//   x = 2^e * m, m in [sqrt2/2, sqrt2), r = (m-1)*rcp(m+1) w/ 1 Newton,
//   log = e*ln2 + 2r*(1 + t/3 + .. + t^6/13).
__device__ __forceinline__ void log8_cr(const float x[8], float out[8]) {
#pragma clang fp contract(off)
  double m[8]; int e[8];
#pragma unroll
  for (int i = 0; i < 8; ++i) {
    uint32_t xb   = __float_as_uint(x[i]);
    uint32_t mant = xb & 0x7FFFFFu;
    int      ee   = (int)(xb >> 23) - 127;
    bool     big  = mant > 0x3504F3u;          // m > sqrt(2)
    e[i] = ee + (big ? 1 : 0);
    uint32_t hi = (big ? 0x3FE00000u : 0x3FF00000u) | (mant >> 3);
    uint32_t lo = mant << 29;
    m[i] = __longlong_as_double(((long long)hi << 32) | (long long)lo);
  }
  SBAR();
  double mp1[8];
#pragma unroll
  for (int i = 0; i < 8; ++i) mp1[i] = m[i] + 1.0;
  SBAR();
  double y[8];
#pragma unroll
  for (int i = 0; i < 8; ++i) y[i] = __builtin_amdgcn_rcp(mp1[i]);
  SBAR();
#pragma unroll
  for (int i = 0; i < 8; ++i) y[i] = fma(fma(-mp1[i], y[i], 1.0), y[i], y[i]);
  SBAR();
  double r[8];
#pragma unroll
  for (int i = 0; i < 8; ++i) r[i] = (m[i] - 1.0) * y[i];
  SBAR();
  double t[8];
#pragma unroll
  for (int i = 0; i < 8; ++i) t[i] = r[i] * r[i];
  SBAR();
  double p[8];
#pragma unroll
  for (int i = 0; i < 8; ++i) p[i] = fma(0.07692307692307693, t[i], 0.09090909090909091);
  SBAR();
#pragma unroll
  for (int i = 0; i < 8; ++i) p[i] = fma(p[i], t[i], 0.1111111111111111);
  SBAR();
#pragma unroll
  for (int i = 0; i < 8; ++i) p[i] = fma(p[i], t[i], 0.14285714285714285);
  SBAR();
#pragma unroll
  for (int i = 0; i < 8; ++i) p[i] = fma(p[i], t[i], 0.2);
  SBAR();
#pragma unroll
  for (int i = 0; i < 8; ++i) p[i] = fma(p[i], t[i], 0.3333333333333333);
  SBAR();
#pragma unroll
  for (int i = 0; i < 8; ++i) p[i] = fma(p[i], t[i], 1.0);
  SBAR();
#pragma unroll
  for (int i = 0; i < 8; ++i) r[i] = r[i] + r[i];       // 2r (exact)
  SBAR();
#pragma unroll
  for (int i = 0; i < 8; ++i) p[i] = r[i] * p[i];       // 2r*q
  SBAR();
#pragma unroll
  for (int i = 0; i < 8; ++i)
    out[i] = (float)fma((double)e[i], 0.6931471805599453, p[i]);
}

// scalar CR log (erfinv path only; same math, unstaged)
__device__ __forceinline__ float log_cr(float x) {
#pragma clang fp contract(off)
  uint32_t xb   = __float_as_uint(x);
  uint32_t mant = xb & 0x7FFFFFu;
  int      e    = (int)(xb >> 23) - 127;
  bool     big  = mant > 0x3504F3u;
  e += big ? 1 : 0;
  uint32_t hi = (big ? 0x3FE00000u : 0x3FF00000u) | (mant >> 3);
  double m = __longlong_as_double(((long long)hi << 32) | (long long)(mant << 29));
  double mp1 = m + 1.0;
  double y = __builtin_amdgcn_rcp(mp1);
  y = fma(fma(-mp1, y, 1.0), y, y);
  double r = (m - 1.0) * y;
  double t = r * r;
  double p = fma(0.07692307692307693, t, 0.09090909090909091);
  p = fma(p, t, 0.1111111111111111);
  p = fma(p, t, 0.14285714285714285);
  p = fma(p, t, 0.2);
  p = fma(p, t, 0.3333333333333333);
  p = fma(p, t, 1.0);
  return (float)fma((double)e, 0.6931471805599453, (r + r) * p);
}

// XLA ErfInv f32 expander (Giles poly), log1p per ElementalIrEmitter::EmitLog1p
__device__ float erfinv_xla(float x) {
#pragma clang fp contract(off)
  float x2  = x * x;
  float nx2 = -x2;
  float l1p;
  if (fabsf(nx2) < 1e-4f) {
    l1p = (-0.5f * nx2 + 1.0f) * nx2;
  } else {
    l1p = log_cr(1.0f + nx2);
  }
  float w = -l1p;
  float p;
  if (w < 5.0f) {
    float ww = w - 2.5f;
    p = 2.81022636e-08f;
    p = p * ww + 3.43273939e-07f;
    p = p * ww + -3.5233877e-06f;
    p = p * ww + -4.39150654e-06f;
    p = p * ww + 0.00021858087f;
    p = p * ww + -0.00125372503f;
    p = p * ww + -0.00417768164f;
    p = p * ww + 0.246640727f;
    p = p * ww + 1.50140941f;
  } else {
    float ww = sqrtf(w) - 3.0f;
    p = -0.000200214257f;
    p = p * ww + 0.000100950558f;
    p = p * ww + 0.00134934322f;
    p = p * ww + -0.00367342844f;
    p = p * ww + 0.00573950773f;
    p = p * ww + -0.0076224613f;
    p = p * ww + 0.00943887047f;
    p = p * ww + 1.00167406f;
    p = p * ww + 2.83297682f;
  }
  return p * x;
}

// R8 = R7 (DPP scans, hoisted loads: 78->63us) + select-phase sync cuts:
// (1) FOUR pre-zeroed histogram buffers, one per radix pass -- no ping-pong,
//     no mid-loop clears -> the clear-before-atomic hazard is gone and each
//     pass needs ONE barrier (publish atomics), not two. 9 -> 5 barriers/row.
// (2) per-WAVE privatized histograms hist[pass][wave][256] (8KB/block):
//     removes inter-wave same-address atomic contention (SQ_LDS_BANK_CONFLICT
//     was a constant 3.56M ~= 5.8us/CU of DS serialization), and same-wave DS
//     ordering lets the pass-3 histogram issue BEFORE the first barrier.
//     Merge cost at selection: 2 uint4 reads + 4 adds.
// Key pipeline / tie-break / epilogue byte-identical to R7 (verified).
__global__ __launch_bounds__(NTHREADS, 7)
void gumbel_topk_mask(const float* __restrict__ wfull,   // (B,C,2S) f32
                      const int*   __restrict__ attn,    // (B,C,S) i32
                      const int*   __restrict__ ids,     // (B,C,S) i32
                      int* __restrict__ out,             // 3x(B,C,S) i32 concat
                      uint32_t kg0, uint32_t kg1, uint32_t kn0, uint32_t kn1) {
#pragma clang fp contract(off)
  const int t    = threadIdx.x;
  const int lane = t & 63;
  const int wid  = t >> 6;            // 0 or 1: which half-row
  const int row  = blockIdx.x;

  __shared__ __align__(16) uint32_t hist[4][2][256];   // [pass][wave][bin]
  __shared__ uint32_t wsum[2];
  __shared__ uint32_t wtot[2];

  const size_t rbase = (size_t)row * SLEN;
  const size_t wbase = (size_t)row * (2 * SLEN);

  // zero MY wave's 4 pass-buffers (wave-ordered vs my later atomics)
#pragma unroll
  for (int p4 = 0; p4 < 4; ++p4)
    ((uint4*)hist[p4][wid])[lane] = make_uint4(0u, 0u, 0u, 0u);

  const int4*   av4 = (const int4*)(attn + rbase);
  const float4* wv4 = (const float4*)(wfull + wbase);
  const int4*   iv4 = (const int4*)(ids + rbase);

  // ---- attention + weight loads issued up front (coalesced); w consumed
  // ~5k cycles later under the threefry/f64 pipeline ----
  int psum = 0;
#pragma unroll
  for (int j = 0; j < CPW; ++j) {
    int4 a = av4[64 * (CPW * wid + j) + lane];
    psum += a.x + a.y + a.z + a.w;
  }
  float4 wC[CPW];
#pragma unroll
  for (int j = 0; j < CPW; ++j) wC[j] = wv4[64 * (CPW * wid + j) + lane];

  // ---- frac (redundant per wave; long f64 chain hides load latency) ----
  uint32_t no0, no1;
  tf2x32(kn0, kn1, 0u, (uint32_t)row, no0, no1);
  float f0  = u01_from_bits(no0 ^ no1);
  float lo  = __uint_as_float(0xBF7FFFFFu);        // nextafter(-1,0)
  float u2  = fmaxf(lo, f0 * 2.0f + lo);           // (1-lo) rounds to 2.0f
  float z   = erfinv_xla(u2);
  float nrm = 1.4142135623730951f * z;
  float frac = 0.15f + 0.0375f * nrm;

  // ---- half-row attention sum: DPP scan, lane63 holds wave total ----
  {
    uint32_t ps = wave_incl_scan((uint32_t)psum);
    if (lane == 63) wsum[wid] = ps;
  }

  // ---- key pipeline: 2 chunk-pairs x 8 elements (forced-ILP) ----
  uint32_t mloc[EPT];
#pragma unroll
  for (int c = 0; c < 2; ++c) {
    const int g0 = CPW * wid + 2 * c;
    float4 wa = wC[2 * c];
    float4 wb = wC[2 * c + 1];
    uint32_t bits[8];
    tf4_bits(kg0, kg1, (uint32_t)(rbase + 256 * g0 + 4 * lane), bits + 0);
    tf4_bits(kg0, kg1, (uint32_t)(rbase + 256 * (g0 + 1) + 4 * lane), bits + 4);
    SBAR();
    float wl8[8] = {wa.x, wa.y, wa.z, wa.w, wb.x, wb.y, wb.z, wb.w};
    float uu[8];
#pragma unroll
    for (int e = 0; e < 8; ++e) {
      float f = u01_from_bits(bits[e]);
      uu[e] = fmaxf(1.17549435e-38f, f * 1.0f + 1.17549435e-38f);
    }
    SBAR();
    float l1[8];
    log8_cr(uu, l1);                       // log u
    float wm[8];
#pragma unroll
    for (int e = 0; e < 8; ++e) wm[e] = fmaxf(wl8[e], 1e-30f);
    float lw[8];
    log8_cr(wm, lw);                       // log w
    float nl1[8];
#pragma unroll
    for (int e = 0; e < 8; ++e) nl1[e] = -l1[e];
    float l2[8];
    log8_cr(nl1, l2);                      // log(-log u); gumbel = -l2
    SBAR();
#pragma unroll
    for (int e = 0; e < 8; ++e) {
      float key = (wl8[e] > 0.0f) ? (lw[e] + (-l2[e])) : -__builtin_inff();
      uint32_t kb = __float_as_uint(key);
      mloc[8 * c + e] = (kb & 0x80000000u) ? ~kb : (kb | 0x80000000u);  // monotone
    }
  }

  // ---- pass-3 histogram into MY wave's buffer, BEFORE the barrier
  // (unconditional: kk-range check only gates the select loop) ----
#pragma unroll
  for (int e = 0; e < EPT; ++e)
    atomicAdd(&hist[3][wid][mloc[e] >> 24], 1u);

  // ids loads: issue now, consumed in epilogue (hidden under the select)
  int4 idsv[CPW];
#pragma unroll
  for (int j = 0; j < CPW; ++j) idsv[j] = iv4[64 * (CPW * wid + j) + lane];

  __syncthreads();                 // B1: wsum + pass-3 hists visible
  int asum = (int)(wsum[0] + wsum[1]);
  int kk = (int)floorf((float)asum * frac);

  // ---- radix-select, 1 barrier/pass (pre-zeroed per-pass buffers) ----
  uint32_t T, r;
  if (kk <= 0)          { T = 0xFFFFFFFFu; r = 0u; }             // mask nothing
  else if (kk >= SLEN)  { T = 0u;          r = (uint32_t)SLEN; } // mask all
  else {
    T = 0u;
    uint32_t need = (uint32_t)kk;
    for (int p = 3; ; --p) {
      // merged read of both waves' pass-p buffers (bins 4*lane..+3)
      uint4 ha = ((const uint4*)hist[p][0])[lane];
      uint4 hb = ((const uint4*)hist[p][1])[lane];
      uint32_t h0 = ha.x + hb.x, h1 = ha.y + hb.y;
      uint32_t h2 = ha.z + hb.z, h3 = ha.w + hb.w;
      uint32_t gs = h0 + h1 + h2 + h3;
      // DPP inclusive prefix -> Gex = total - P (sum over lanes > me)
      uint32_t P     = wave_incl_scan(gs);
      uint32_t total = (uint32_t)__builtin_amdgcn_readlane((int)P, 63);
      uint32_t Gex   = total - P;
      uint32_t S3 = Gex;
      uint32_t S2 = S3 + h3;
      uint32_t S1 = S2 + h2;
      uint32_t S0 = S1 + h1;
      uint32_t hh[4] = {h0, h1, h2, h3};
      uint32_t SS[4] = {S0, S1, S2, S3};
      int haswin = 0; uint32_t binv = 0u, remv = 0u; int donev = 0;
#pragma unroll
      for (int i = 0; i < 4; ++i) {
        if (hh[i] && SS[i] < need && need <= SS[i] + hh[i]) {   // unique winner
          haswin = 1;
          binv = (uint32_t)(4 * lane + i);
          remv = need - SS[i];
          donev = (remv == hh[i]) ? 1 : 0;   // whole bin taken: low bytes stay 0
        }
      }
      unsigned long long wmask = __ballot(haswin);
      int src = (int)(__ffsll((unsigned long long)wmask) - 1);
      uint32_t bin = (uint32_t)__builtin_amdgcn_readlane((int)binv, src);
      uint32_t rem = (uint32_t)__builtin_amdgcn_readlane((int)remv, src);
      int     done = __builtin_amdgcn_readlane(donev, src);
      T |= bin << (8 * p);
      need = rem;
      if (done || p == 0) { r = rem; break; }            // uniform block-wide
      // histogram digit p-1 of survivors into MY wave's pass-(p-1) buffer
      const int sh = 8 * p;
#pragma unroll
      for (int e = 0; e < EPT; ++e) {
        uint32_t m = mloc[e];
        if ((m >> sh) == (T >> sh))
          atomicAdd(&hist[p - 1][wid][(m >> (sh - 8)) & 255u], 1u);
      }
      __syncthreads();                                   // publish pass p-1
    }
  }

  // ---- stable tie-break in INDEX order (DPP packed scan) ----
  uint32_t cnt[CPW];
#pragma unroll
  for (int j = 0; j < CPW; ++j) {
    uint32_t c = 0;
#pragma unroll
    for (int e = 0; e < 4; ++e) c += (mloc[4 * j + e] == T) ? 1u : 0u;
    cnt[j] = c;
  }
  uint32_t incl[2];
#pragma unroll
  for (int q = 0; q < 2; ++q)
    incl[q] = wave_incl_scan(cnt[2 * q] | (cnt[2 * q + 1] << 16));
  uint32_t Spre[CPW], tot[CPW];
#pragma unroll
  for (int q = 0; q < 2; ++q) {
    uint32_t t63 = (uint32_t)__builtin_amdgcn_readlane((int)incl[q], 63);
    tot[2 * q]      = t63 & 0xFFFFu;
    tot[2 * q + 1]  = t63 >> 16;
    Spre[2 * q]     = (incl[q] & 0xFFFFu) - cnt[2 * q];
    Spre[2 * q + 1] = (incl[q] >> 16)     - cnt[2 * q + 1];
  }
  if (lane == 0) wtot[wid] = tot[0] + tot[1] + tot[2] + tot[3];
  __syncthreads();
  uint32_t C = wid ? wtot[0] : 0u;   // eq-count in the other wave's earlier half

  // ---- epilogue: masked writes (coalesced, fire-and-forget) ----
  int4* po = (int4*)(out + rbase);
  int4* pm = (int4*)(out + TOKENS_PER_OUT + rbase);
  int4* pl = (int4*)(out + 2 * TOKENS_PER_OUT + rbase);
#pragma unroll
  for (int j = 0; j < CPW; ++j) {
    uint32_t excl = C + Spre[j];
    int4 iv = idsv[j];
    int idv[4] = {iv.x, iv.y, iv.z, iv.w};
    int oid[4], omk[4], olb[4];
#pragma unroll
    for (int e = 0; e < 4; ++e) {
      uint32_t m = mloc[4 * j + e];
      bool eq  = (m == T);
      bool msk = (m > T) || (eq && (excl < r));
      excl += eq ? 1u : 0u;
      oid[e] = msk ? 103 : idv[e];      // MASK_ID
      omk[e] = msk ? 1 : 0;
      olb[e] = msk ? -1 : 0;
    }
    const int gi = 64 * (CPW * wid + j) + lane;
    po[gi] = make_int4(oid[0], oid[1], oid[2], oid[3]);
    pm[gi] = make_int4(omk[0], omk[1], omk[2], omk[3]);
    pl[gi] = make_int4(olb[0], olb[1], olb[2], olb[3]);
    C += tot[j];
  }
}

extern "C" void kernel_launch(void* const* d_in, const int* in_sizes, int n_in,
                              void* d_out, int out_size, void* d_ws, size_t ws_size,
                              hipStream_t stream) {
  (void)n_in; (void)d_ws; (void)ws_size; (void)out_size;
  const float* wfull = (const float*)d_in[0];   // my_attention_mask (B,C,2S)
  const int*   attn  = (const int*)d_in[1];     // attention_mask    (B,C,S)
  const int*   ids   = (const int*)d_in[2];     // input_ids         (B,C,S)
  int* out = (int*)d_out;

  // jax.random.key(42) -> (0,42); partitionable split: kg=enc(key,(0,0)), kn=enc(key,(0,1))
  uint32_t kg0, kg1, kn0, kn1, o0, o1;
  tf2x32(0u, 42u, 0u, 0u, o0, o1); kg0 = o0; kg1 = o1;
  tf2x32(0u, 42u, 0u, 1u, o0, o1); kn0 = o0; kn1 = o1;

  int rows = in_sizes[1] / SLEN;                // 4096
  hipLaunchKernelGGL(gumbel_topk_mask, dim3(rows), dim3(NTHREADS),
                     0, stream, wfull, attn, ids, out, kg0, kg1, kn0, kn1);
}

// Round 9
// 200.254 us; speedup vs baseline: 1.1834x; 1.0100x over previous
//
#include <hip/hip_runtime.h>
#include <stdint.h>
#include <math.h>

#define SLEN 2048
#define EPT 32               // elements per lane: one wave owns a full row
#define NTHREADS 256         // 4 waves = 4 independent rows per block
#define ROWS_PER_BLOCK 4
#define NCHUNK 8             // row = 8 chunks of 256 el (64 lanes x 4 el)
#define TOKENS_PER_OUT 8388608   // 1024*4*2048

// ---------- Threefry-2x32, 20 rounds, matches jax._src.prng ----------
__host__ __device__ __forceinline__ void tf2x32(uint32_t k0, uint32_t k1,
                                                uint32_t x0, uint32_t x1,
                                                uint32_t &o0, uint32_t &o1) {
  uint32_t ks2 = 0x1BD11BDAu ^ k0 ^ k1;
  x0 += k0; x1 += k1;
#define TFR(r) { x0 += x1; x1 = (x1 << (r)) | (x1 >> (32 - (r))); x1 ^= x0; }
  TFR(13) TFR(15) TFR(26) TFR(6)
  x0 += k1;  x1 += ks2 + 1u;
  TFR(17) TFR(29) TFR(16) TFR(24)
  x0 += ks2; x1 += k0 + 2u;
  TFR(13) TFR(15) TFR(26) TFR(6)
  x0 += k0;  x1 += k1 + 3u;
  TFR(17) TFR(29) TFR(16) TFR(24)
  x0 += k1;  x1 += ks2 + 4u;
  TFR(13) TFR(15) TFR(26) TFR(6)
  x0 += ks2; x1 += k0 + 5u;
#undef TFR
  o0 = x0; o1 = x1;
}

// 4 independent threefry streams; sched_barrier after each round keeps the
// 4-wide interleave intact through the machine scheduler.
__device__ __forceinline__ void tf4_bits(uint32_t k0, uint32_t k1,
                                         uint32_t cbase, uint32_t bits[4]) {
  const uint32_t ks2 = 0x1BD11BDAu ^ k0 ^ k1;
  uint32_t x0[4], x1[4];
#pragma unroll
  for (int i = 0; i < 4; ++i) { x0[i] = k0; x1[i] = (cbase + (uint32_t)i) + k1; }
#define TFR4(r)                                                         \
  _Pragma("unroll")                                                     \
  for (int i = 0; i < 4; ++i) {                                         \
    x0[i] += x1[i];                                                     \
    x1[i] = (x1[i] << (r)) | (x1[i] >> (32 - (r)));                     \
    x1[i] ^= x0[i];                                                     \
  }                                                                     \
  __builtin_amdgcn_sched_barrier(0);
#define INJ4(a, b)                                                      \
  _Pragma("unroll")                                                     \
  for (int i = 0; i < 4; ++i) { x0[i] += (a); x1[i] += (b); }
  TFR4(13) TFR4(15) TFR4(26) TFR4(6)
  INJ4(k1, ks2 + 1u)
  TFR4(17) TFR4(29) TFR4(16) TFR4(24)
  INJ4(ks2, k0 + 2u)
  TFR4(13) TFR4(15) TFR4(26) TFR4(6)
  INJ4(k0, k1 + 3u)
  TFR4(17) TFR4(29) TFR4(16) TFR4(24)
  INJ4(k1, ks2 + 4u)
  TFR4(13) TFR4(15) TFR4(26) TFR4(6)
  INJ4(ks2, k0 + 5u)
#undef TFR4
#undef INJ4
#pragma unroll
  for (int i = 0; i < 4; ++i) bits[i] = x0[i] ^ x1[i];
}

__device__ __forceinline__ float u01_from_bits(uint32_t bits) {
  return __uint_as_float((bits >> 9) | 0x3F800000u) - 1.0f;
}

#define SBAR() __builtin_amdgcn_sched_barrier(0)

// ---- DPP wave64 scan primitives (VALU ~2cy/step vs ds_bpermute ~30-40cy) ----
template<int CTRL, int RMASK>
__device__ __forceinline__ uint32_t dpp_mov0(uint32_t x) {
  // invalid/masked lanes yield 0 (old=0, bound_ctrl=false)
  return (uint32_t)__builtin_amdgcn_update_dpp(0, (int)x, CTRL, RMASK, 0xF, false);
}
// classic GCN wave64 inclusive prefix sum: row_shr 1/2/4/8, bcast15->rows 1,3,
// bcast31->rows 2,3
__device__ __forceinline__ uint32_t wave_incl_scan(uint32_t x) {
  x += dpp_mov0<0x111, 0xF>(x);   // row_shr:1
  x += dpp_mov0<0x112, 0xF>(x);   // row_shr:2
  x += dpp_mov0<0x114, 0xF>(x);   // row_shr:4
  x += dpp_mov0<0x118, 0xF>(x);   // row_shr:8
  x += dpp_mov0<0x142, 0xA>(x);   // row_bcast:15 into rows 1,3
  x += dpp_mov0<0x143, 0xC>(x);   // row_bcast:31 into rows 2,3
  return x;
}

// 8 correctly-rounded-quality f32 logs (positive normal f32 inputs), staged
// 8-wide with hard sched barriers so dependent f64 ops sit ~8 instrs apart.
// Bit-identical to the verified scalar math:
//   x = 2^e * m, m in [sqrt2/2, sqrt2), r = (m-1)*rcp(m+1) w/ 1 Newton,
//   log = e*ln2 + 2r*(1 + t/3 + .. + t^6/13).
__device__ __forceinline__ void log8_cr(const float x[8], float out[8]) {
#pragma clang fp contract(off)
  double m[8]; int e[8];
#pragma unroll
  for (int i = 0; i < 8; ++i) {
    uint32_t xb   = __float_as_uint(x[i]);
    uint32_t mant = xb & 0x7FFFFFu;
    int      ee   = (int)(xb >> 23) - 127;
    bool     big  = mant > 0x3504F3u;          // m > sqrt(2)
    e[i] = ee + (big ? 1 : 0);
    uint32_t hi = (big ? 0x3FE00000u : 0x3FF00000u) | (mant >> 3);
    uint32_t lo = mant << 29;
    m[i] = __longlong_as_double(((long long)hi << 32) | (long long)lo);
  }
  SBAR();
  double mp1[8];
#pragma unroll
  for (int i = 0; i < 8; ++i) mp1[i] = m[i] + 1.0;
  SBAR();
  double y[8];
#pragma unroll
  for (int i = 0; i < 8; ++i) y[i] = __builtin_amdgcn_rcp(mp1[i]);
  SBAR();
#pragma unroll
  for (int i = 0; i < 8; ++i) y[i] = fma(fma(-mp1[i], y[i], 1.0), y[i], y[i]);
  SBAR();
  double r[8];
#pragma unroll
  for (int i = 0; i < 8; ++i) r[i] = (m[i] - 1.0) * y[i];
  SBAR();
  double t[8];
#pragma unroll
  for (int i = 0; i < 8; ++i) t[i] = r[i] * r[i];
  SBAR();
  double p[8];
#pragma unroll
  for (int i = 0; i < 8; ++i) p[i] = fma(0.07692307692307693, t[i], 0.09090909090909091);
  SBAR();
#pragma unroll
  for (int i = 0; i < 8; ++i) p[i] = fma(p[i], t[i], 0.1111111111111111);
  SBAR();
#pragma unroll
  for (int i = 0; i < 8; ++i) p[i] = fma(p[i], t[i], 0.14285714285714285);
  SBAR();
#pragma unroll
  for (int i = 0; i < 8; ++i) p[i] = fma(p[i], t[i], 0.2);
  SBAR();
#pragma unroll
  for (int i = 0; i < 8; ++i) p[i] = fma(p[i], t[i], 0.3333333333333333);
  SBAR();
#pragma unroll
  for (int i = 0; i < 8; ++i) p[i] = fma(p[i], t[i], 1.0);
  SBAR();
#pragma unroll
  for (int i = 0; i < 8; ++i) r[i] = r[i] + r[i];       // 2r (exact)
  SBAR();
#pragma unroll
  for (int i = 0; i < 8; ++i) p[i] = r[i] * p[i];       // 2r*q
  SBAR();
#pragma unroll
  for (int i = 0; i < 8; ++i)
    out[i] = (float)fma((double)e[i], 0.6931471805599453, p[i]);
}

// scalar CR log (erfinv path only; same math, unstaged)
__device__ __forceinline__ float log_cr(float x) {
#pragma clang fp contract(off)
  uint32_t xb   = __float_as_uint(x);
  uint32_t mant = xb & 0x7FFFFFu;
  int      e    = (int)(xb >> 23) - 127;
  bool     big  = mant > 0x3504F3u;
  e += big ? 1 : 0;
  uint32_t hi = (big ? 0x3FE00000u : 0x3FF00000u) | (mant >> 3);
  double m = __longlong_as_double(((long long)hi << 32) | (long long)(mant << 29));
  double mp1 = m + 1.0;
  double y = __builtin_amdgcn_rcp(mp1);
  y = fma(fma(-mp1, y, 1.0), y, y);
  double r = (m - 1.0) * y;
  double t = r * r;
  double p = fma(0.07692307692307693, t, 0.09090909090909091);
  p = fma(p, t, 0.1111111111111111);
  p = fma(p, t, 0.14285714285714285);
  p = fma(p, t, 0.2);
  p = fma(p, t, 0.3333333333333333);
  p = fma(p, t, 1.0);
  return (float)fma((double)e, 0.6931471805599453, (r + r) * p);
}

// XLA ErfInv f32 expander (Giles poly), log1p per ElementalIrEmitter::EmitLog1p
__device__ float erfinv_xla(float x) {
#pragma clang fp contract(off)
  float x2  = x * x;
  float nx2 = -x2;
  float l1p;
  if (fabsf(nx2) < 1e-4f) {
    l1p = (-0.5f * nx2 + 1.0f) * nx2;
  } else {
    l1p = log_cr(1.0f + nx2);
  }
  float w = -l1p;
  float p;
  if (w < 5.0f) {
    float ww = w - 2.5f;
    p = 2.81022636e-08f;
    p = p * ww + 3.43273939e-07f;
    p = p * ww + -3.5233877e-06f;
    p = p * ww + -4.39150654e-06f;
    p = p * ww + 0.00021858087f;
    p = p * ww + -0.00125372503f;
    p = p * ww + -0.00417768164f;
    p = p * ww + 0.246640727f;
    p = p * ww + 1.50140941f;
  } else {
    float ww = sqrtf(w) - 3.0f;
    p = -0.000200214257f;
    p = p * ww + 0.000100950558f;
    p = p * ww + 0.00134934322f;
    p = p * ww + -0.00367342844f;
    p = p * ww + 0.00573950773f;
    p = p * ww + -0.0076224613f;
    p = p * ww + 0.00943887047f;
    p = p * ww + 1.00167406f;
    p = p * ww + 2.83297682f;
  }
  return p * x;
}

// R9 = R3's wave-per-row structure (verified, zero __syncthreads) + R7's DPP
// scans/readlane broadcasts/hoisted loads + R8's pre-zeroed per-pass buffers.
// Rationale: R8 proved barriers-count and atomic contention are not the
// residual 22us (both changed, null; SQ_LDS_BANK_CONFLICT bit-identical =>
// intra-wave scatter, data-fixed). The remaining lever: wave AUTONOMY -- a
// barrier-paired select chain (~1.5-2k cy of LDS-latency + scan + broadcast)
// stalls both waves in lockstep; with fully wave-local rows, waves drift
// apart and each SIMD always has a pipeline-phase wave to issue during
// another wave's select chain. Same-wave DS ordering (lgkmcnt + wave_barrier)
// replaces all block syncs -- the R2/R3-verified pattern.
__global__ __launch_bounds__(NTHREADS, 4)
void gumbel_topk_mask(const float* __restrict__ wfull,   // (B,C,2S) f32
                      const int*   __restrict__ attn,    // (B,C,S) i32
                      const int*   __restrict__ ids,     // (B,C,S) i32
                      int* __restrict__ out,             // 3x(B,C,S) i32 concat
                      uint32_t kg0, uint32_t kg1, uint32_t kn0, uint32_t kn1) {
#pragma clang fp contract(off)
  const int t    = threadIdx.x;
  const int lane = t & 63;
  const int wid  = t >> 6;
  const int row  = blockIdx.x * ROWS_PER_BLOCK + wid;

  __shared__ __align__(16) uint32_t hist[ROWS_PER_BLOCK][4][256];  // [wave][pass][bin]

  const size_t rbase = (size_t)row * SLEN;
  const size_t wbase = (size_t)row * (2 * SLEN);

  // zero MY wave's 4 pass-buffers (same-wave DS ordering vs later atomics)
#pragma unroll
  for (int p4 = 0; p4 < 4; ++p4)
    ((uint4*)hist[wid][p4])[lane] = make_uint4(0u, 0u, 0u, 0u);

  const int4*   av4 = (const int4*)(attn + rbase);
  const float4* wv4 = (const float4*)(wfull + wbase);
  const int4*   iv4 = (const int4*)(ids + rbase);

  // ---- attn + w loads issued up front (coalesced: lane stride 16B);
  // w consumed ~5k cycles later under the threefry/f64 pipeline ----
  int psum = 0;
#pragma unroll
  for (int j = 0; j < NCHUNK; ++j) {
    int4 a = av4[64 * j + lane];
    psum += a.x + a.y + a.z + a.w;
  }
  float4 wC[NCHUNK];
#pragma unroll
  for (int j = 0; j < NCHUNK; ++j) wC[j] = wv4[64 * j + lane];

  // ---- frac (load-independent long f64 chain; hides load latency) ----
  uint32_t no0, no1;
  tf2x32(kn0, kn1, 0u, (uint32_t)row, no0, no1);
  float f0  = u01_from_bits(no0 ^ no1);
  float lo  = __uint_as_float(0xBF7FFFFFu);        // nextafter(-1,0)
  float u2  = fmaxf(lo, f0 * 2.0f + lo);           // (1-lo) rounds to 2.0f
  float z   = erfinv_xla(u2);
  float nrm = 1.4142135623730951f * z;
  float frac = 0.15f + 0.0375f * nrm;

  // ---- row attention sum: DPP scan + readlane(63) -- no LDS, no barrier ----
  uint32_t ps = wave_incl_scan((uint32_t)psum);
  int asum = (int)__builtin_amdgcn_readlane((int)ps, 63);
  int kk = (int)floorf((float)asum * frac);

  // ---- key pipeline: 4 chunk-pairs x 8 elements (forced-ILP) ----
  // mloc[4*j + e] <=> chunk j (indices 256j + 4*lane + e)
  uint32_t mloc[EPT];
#pragma unroll
  for (int c = 0; c < 4; ++c) {
    float4 wa = wC[2 * c], wb = wC[2 * c + 1];
    uint32_t bits[8];
    tf4_bits(kg0, kg1, (uint32_t)(rbase + 256 * (2 * c)     + 4 * lane), bits + 0);
    tf4_bits(kg0, kg1, (uint32_t)(rbase + 256 * (2 * c + 1) + 4 * lane), bits + 4);
    SBAR();
    float wl8[8] = {wa.x, wa.y, wa.z, wa.w, wb.x, wb.y, wb.z, wb.w};
    float uu[8];
#pragma unroll
    for (int e = 0; e < 8; ++e) {
      float f = u01_from_bits(bits[e]);
      uu[e] = fmaxf(1.17549435e-38f, f * 1.0f + 1.17549435e-38f);
    }
    SBAR();
    float l1[8];
    log8_cr(uu, l1);                       // log u
    float wm[8];
#pragma unroll
    for (int e = 0; e < 8; ++e) wm[e] = fmaxf(wl8[e], 1e-30f);
    float lw[8];
    log8_cr(wm, lw);                       // log w
    float nl1[8];
#pragma unroll
    for (int e = 0; e < 8; ++e) nl1[e] = -l1[e];
    float l2[8];
    log8_cr(nl1, l2);                      // log(-log u); gumbel = -l2
    SBAR();
#pragma unroll
    for (int e = 0; e < 8; ++e) {
      float key = (wl8[e] > 0.0f) ? (lw[e] + (-l2[e])) : -__builtin_inff();
      uint32_t kb = __float_as_uint(key);
      mloc[8 * c + e] = (kb & 0x80000000u) ? ~kb : (kb | 0x80000000u);  // monotone
    }
  }

  // ids loads: issue now, consumed in epilogue (hidden under the select)
  int4 idsv[NCHUNK];
#pragma unroll
  for (int j = 0; j < NCHUNK; ++j) idsv[j] = iv4[64 * j + lane];

  // ---- wave-private radix-select of the k-th largest key ----
  uint32_t T, r;
  if (kk <= 0)          { T = 0xFFFFFFFFu; r = 0u; }             // mask nothing
  else if (kk >= SLEN)  { T = 0u;          r = (uint32_t)SLEN; } // mask all
  else {
    T = 0u;
    uint32_t need = (uint32_t)kk;
    asm volatile("s_waitcnt lgkmcnt(0)" ::: "memory");   // zeros done
#pragma unroll
    for (int e = 0; e < EPT; ++e)
      atomicAdd(&hist[wid][3][mloc[e] >> 24], 1u);
    for (int p = 3; ; --p) {
      asm volatile("s_waitcnt lgkmcnt(0)" ::: "memory");   // atomics visible
      __builtin_amdgcn_wave_barrier();
      SBAR();
      uint4 hq = ((const uint4*)hist[wid][p])[lane];       // bins 4*lane..+3
      uint32_t gs = hq.x + hq.y + hq.z + hq.w;
      // DPP inclusive prefix -> Gex = total - P (sum over lanes > me)
      uint32_t P     = wave_incl_scan(gs);
      uint32_t total = (uint32_t)__builtin_amdgcn_readlane((int)P, 63);
      uint32_t Gex   = total - P;
      uint32_t S3 = Gex;
      uint32_t S2 = S3 + hq.w;
      uint32_t S1 = S2 + hq.z;
      uint32_t S0 = S1 + hq.y;
      uint32_t hh[4] = {hq.x, hq.y, hq.z, hq.w};
      uint32_t SS[4] = {S0, S1, S2, S3};
      int haswin = 0; uint32_t binv = 0u, remv = 0u; int donev = 0;
#pragma unroll
      for (int i = 0; i < 4; ++i) {
        if (hh[i] && SS[i] < need && need <= SS[i] + hh[i]) {   // unique winner
          haswin = 1;
          binv = (uint32_t)(4 * lane + i);
          remv = need - SS[i];
          donev = (remv == hh[i]) ? 1 : 0;   // whole bin taken: low bytes stay 0
        }
      }
      unsigned long long wmask = __ballot(haswin);
      int src = (int)(__ffsll((unsigned long long)wmask) - 1);
      uint32_t bin = (uint32_t)__builtin_amdgcn_readlane((int)binv, src);
      uint32_t rem = (uint32_t)__builtin_amdgcn_readlane((int)remv, src);
      int     done = __builtin_amdgcn_readlane(donev, src);
      T |= bin << (8 * p);
      need = rem;
      if (done || p == 0) { r = rem; break; }
      // histogram digit p-1 of survivors into MY pass-(p-1) buffer
      const int sh = 8 * p;
#pragma unroll
      for (int e = 0; e < EPT; ++e) {
        uint32_t m = mloc[e];
        if ((m >> sh) == (T >> sh))
          atomicAdd(&hist[wid][p - 1][(m >> (sh - 8)) & 255u], 1u);
      }
    }
  }

  // ---- stable tie-break in INDEX order across interleaved chunks:
  // 4 packed 16-bit-field DPP scans + per-chunk totals (all in-wave) ----
  uint32_t cnt[NCHUNK];
#pragma unroll
  for (int j = 0; j < NCHUNK; ++j) {
    uint32_t c = 0;
#pragma unroll
    for (int e = 0; e < 4; ++e) c += (mloc[4 * j + e] == T) ? 1u : 0u;
    cnt[j] = c;
  }
  uint32_t incl[4];
#pragma unroll
  for (int q = 0; q < 4; ++q)
    incl[q] = wave_incl_scan(cnt[2 * q] | (cnt[2 * q + 1] << 16));
  uint32_t Spre[NCHUNK], tot[NCHUNK];
#pragma unroll
  for (int q = 0; q < 4; ++q) {
    uint32_t t63 = (uint32_t)__builtin_amdgcn_readlane((int)incl[q], 63);
    tot[2 * q]      = t63 & 0xFFFFu;
    tot[2 * q + 1]  = t63 >> 16;
    Spre[2 * q]     = (incl[q] & 0xFFFFu) - cnt[2 * q];
    Spre[2 * q + 1] = (incl[q] >> 16)     - cnt[2 * q + 1];
  }

  // ---- epilogue: masked writes (coalesced, fire-and-forget) ----
  int4* po = (int4*)(out + rbase);
  int4* pm = (int4*)(out + TOKENS_PER_OUT + rbase);
  int4* pl = (int4*)(out + 2 * TOKENS_PER_OUT + rbase);
  uint32_t C = 0;   // eq-count in chunks before j (uniform across lanes)
#pragma unroll
  for (int j = 0; j < NCHUNK; ++j) {
    uint32_t excl = C + Spre[j];
    int4 iv = idsv[j];
    int idv[4] = {iv.x, iv.y, iv.z, iv.w};
    int oid[4], omk[4], olb[4];
#pragma unroll
    for (int e = 0; e < 4; ++e) {
      uint32_t m = mloc[4 * j + e];
      bool eq  = (m == T);
      bool msk = (m > T) || (eq && (excl < r));
      excl += eq ? 1u : 0u;
      oid[e] = msk ? 103 : idv[e];      // MASK_ID
      omk[e] = msk ? 1 : 0;
      olb[e] = msk ? -1 : 0;
    }
    po[64 * j + lane] = make_int4(oid[0], oid[1], oid[2], oid[3]);
    pm[64 * j + lane] = make_int4(omk[0], omk[1], omk[2], omk[3]);
    pl[64 * j + lane] = make_int4(olb[0], olb[1], olb[2], olb[3]);
    C += tot[j];
  }
}

extern "C" void kernel_launch(void* const* d_in, const int* in_sizes, int n_in,
                              void* d_out, int out_size, void* d_ws, size_t ws_size,
                              hipStream_t stream) {
  (void)n_in; (void)d_ws; (void)ws_size; (void)out_size;
  const float* wfull = (const float*)d_in[0];   // my_attention_mask (B,C,2S)
  const int*   attn  = (const int*)d_in[1];     // attention_mask    (B,C,S)
  const int*   ids   = (const int*)d_in[2];     // input_ids         (B,C,S)
  int* out = (int*)d_out;

  // jax.random.key(42) -> (0,42); partitionable split: kg=enc(key,(0,0)), kn=enc(key,(0,1))
  uint32_t kg0, kg1, kn0, kn1, o0, o1;
  tf2x32(0u, 42u, 0u, 0u, o0, o1); kg0 = o0; kg1 = o1;
  tf2x32(0u, 42u, 0u, 1u, o0, o1); kn0 = o0; kn1 = o1;

  int rows = in_sizes[1] / SLEN;                // 4096
  hipLaunchKernelGGL(gumbel_topk_mask, dim3(rows / ROWS_PER_BLOCK), dim3(NTHREADS),
                     0, stream, wfull, attn, ids, out, kg0, kg1, kn0, kn1);
}